// Round 4
// baseline (221.351 us; speedup 1.0000x reference)
//
#include <hip/hip_runtime.h>

// Shapes: genes[32][2048][4], smiles[32][2048][1024], w_ngf[4], w_genes[2048][512],
//         b_genes[512], w_smiles[1024][512], b_smiles[512], v[512] -> out[32][1024]

typedef __bf16 bf16_t;
typedef bf16_t bf16x8 __attribute__((ext_vector_type(8)));
typedef float f32x4 __attribute__((ext_vector_type(4)));

__device__ __forceinline__ unsigned short f32_to_bf16_rne(float f) {
    unsigned int u = __builtin_bit_cast(unsigned int, f);
    u = (u + 0x7FFFu + ((u >> 16) & 1u)) >> 16;
    return (unsigned short)u;
}

__device__ __forceinline__ float fast_tanh(float x) {
    float cx = fminf(fmaxf(x, -30.f), 30.f);
    float e = __expf(2.f * cx);
    return (e - 1.f) / (e + 1.f);
}

// lgkm-only drain + raw barrier: ds_writes visible to other waves, but VMEM
// (the 2-deep A prefetch) stays in flight across the tile boundary.
__device__ __forceinline__ void lds_fence_barrier() {
    asm volatile("s_waitcnt lgkmcnt(0)" ::: "memory");
    __builtin_amdgcn_sched_barrier(0);
    __builtin_amdgcn_s_barrier();
}

// K0b: pack w_smiles [1024][512] f32 into FRAGMENT-MAJOR bf16 (contiguous 1KB frags).
// Bp[frag=atile*32+gks][lane][e] = w[gks*32 + (lane>>4)*8 + e][atile*16 + (lane&15)]
__global__ void k0b_pack(const float* __restrict__ w, unsigned short* __restrict__ Bp) {
    int bid  = blockIdx.x;        // 1024 = 32 atiles * 32 gks
    int lane = threadIdx.x;       // 64
    int atile = bid >> 5, gks = bid & 31;
    int col = atile * 16 + (lane & 15);
    int k0  = gks * 32 + (lane >> 4) * 8;
    unsigned short us[8];
#pragma unroll
    for (int e = 0; e < 8; ++e)
        us[e] = f32_to_bf16_rne(w[(size_t)(k0 + e) * 512 + col]);
    *(uint4*)(Bp + (size_t)bid * 512 + lane * 8) = *(const uint4*)us;
}

// K1a: gc[b][g] = dot(genes[b][g][0..3], w_ngf)
__global__ void k1a_gc(const float4* __restrict__ genes, const float* __restrict__ wngf,
                       float* __restrict__ gc) {
    int i = blockIdx.x * 256 + threadIdx.x;   // 65536 = 32*2048
    float4 g = genes[i];
    gc[i] = g.x * wngf[0] + g.y * wngf[1] + g.z * wngf[2] + g.w * wngf[3];
}

// K1b: x[b][a] += sum_{g in chunk} gc[b][g] * w_genes[g][a]   (x pre-zeroed)
__global__ void k1b_x(const float* __restrict__ gc, const float* __restrict__ wg,
                      float* __restrict__ x) {
    __shared__ float gcl[256];
    int bx = blockIdx.x;              // 512 = 32 b * 2 a-halves * 8 g-chunks
    int b = bx >> 4, ah = (bx >> 3) & 1, gch = bx & 7;
    int g0 = gch * 256;
    gcl[threadIdx.x] = gc[b * 2048 + g0 + threadIdx.x];
    __syncthreads();
    int a = ah * 256 + threadIdx.x;
    float s = 0.f;
#pragma unroll 8
    for (int g = 0; g < 256; ++g) s += gcl[g] * wg[(size_t)(g0 + g) * 512 + a];
    atomicAdd(&x[b * 512 + a], s);
}

// K2: fused GEMM + tanh + dot(v) -> scores.
// BK=128 double-buffered LDS. Schedule per tile t (reading buf cur = tile t):
//   COMPUTE ks{0,1} -> CONVWRITE A(t+1) into cur^1 (vmcnt wait covered by MFMAs)
//   -> issue A(t+2) loads -> COMPUTE ks{2,3} -> lgkm drain + RAW barrier
// A prefetch is 2-deep and survives the barrier (no vmcnt(0) drain).
__global__ __launch_bounds__(512, 4) void k2_scores(
    const float* __restrict__ smiles,
    const unsigned short* __restrict__ Bp,
    const float* __restrict__ xraw,
    const float* __restrict__ b_genes,
    const float* __restrict__ b_smiles,
    const float* __restrict__ v,
    float* __restrict__ scores)
{
    __shared__ unsigned short A_lds[2 * 64 * 128];   // 32 KB, XOR-swizzled 256B rows
    const int tid  = threadIdx.x;
    const int wave = tid >> 6;
    const int lane = tid & 63;
    const int l15  = lane & 15;
    const int l4   = lane >> 4;
    const int gm0  = blockIdx.x * 64;            // 1024 blocks
    const int bidx = gm0 >> 11;
    const int wbase = wave * 64;

    // wave's packed-B base: fragments (wave*4+nt)*32 + gks, each 1KB
    const unsigned short* bpp = Bp + (size_t)(wave * 128) * 512 + lane * 8;

    // staging geometry: thread owns 16 consecutive floats of the 64x128 tile
    const int srow = tid >> 3;                   // 0..63
    const float* sptr = smiles + (size_t)(gm0 + srow) * 1024 + (tid & 7) * 16;
    const int sswz = (srow & 7) << 4;
    char* wr0 = (char*)A_lds + srow * 256 + (((tid & 7) * 32) ^ sswz);
    char* wr1 = (char*)A_lds + srow * 256 + ((((tid & 7) * 32) + 16) ^ sswz);

    float4 st0, st1, st2, st3;

    const f32x4 zero4 = {0.f, 0.f, 0.f, 0.f};
    f32x4 acc[4][4];
#pragma unroll
    for (int mt = 0; mt < 4; ++mt)
#pragma unroll
        for (int nt = 0; nt < 4; ++nt)
            acc[mt][nt] = zero4;

#define LOADREGS(kt)                                   \
    {   const float* p = sptr + (kt) * 128;            \
        st0 = *(const float4*)(p);                     \
        st1 = *(const float4*)(p + 4);                 \
        st2 = *(const float4*)(p + 8);                 \
        st3 = *(const float4*)(p + 12); }

#define CONVWRITE(buf)                                                     \
    {   union { unsigned short us[8]; uint4 u4; } pa, pb;                  \
        pa.us[0] = f32_to_bf16_rne(st0.x); pa.us[1] = f32_to_bf16_rne(st0.y); \
        pa.us[2] = f32_to_bf16_rne(st0.z); pa.us[3] = f32_to_bf16_rne(st0.w); \
        pa.us[4] = f32_to_bf16_rne(st1.x); pa.us[5] = f32_to_bf16_rne(st1.y); \
        pa.us[6] = f32_to_bf16_rne(st1.z); pa.us[7] = f32_to_bf16_rne(st1.w); \
        pb.us[0] = f32_to_bf16_rne(st2.x); pb.us[1] = f32_to_bf16_rne(st2.y); \
        pb.us[2] = f32_to_bf16_rne(st2.z); pb.us[3] = f32_to_bf16_rne(st2.w); \
        pb.us[4] = f32_to_bf16_rne(st3.x); pb.us[5] = f32_to_bf16_rne(st3.y); \
        pb.us[6] = f32_to_bf16_rne(st3.z); pb.us[7] = f32_to_bf16_rne(st3.w); \
        *(uint4*)(wr0 + (buf) * 16384) = pa.u4;                            \
        *(uint4*)(wr1 + (buf) * 16384) = pb.u4; }

#define COMPUTE2(cur, kt, ksb)                                                \
    _Pragma("unroll")                                                         \
    for (int ks4 = (ksb); ks4 < (ksb) + 2; ++ks4) {                           \
        int gks = (kt) * 4 + ks4;                                             \
        bf16x8 af[4], bfb[4];                                                 \
        _Pragma("unroll")                                                     \
        for (int nt = 0; nt < 4; ++nt)                                        \
            bfb[nt] = *(const bf16x8*)(bpp + (nt * 32 + gks) * 512);          \
        _Pragma("unroll")                                                     \
        for (int mt = 0; mt < 4; ++mt) {                                      \
            int row = mt * 16 + l15;                                          \
            int byteoff = (cur) * 16384 + row * 256 +                         \
                          ((ks4 * 64 + l4 * 16) ^ ((row & 7) << 4));          \
            af[mt] = *(const bf16x8*)((const char*)A_lds + byteoff);          \
        }                                                                     \
        __builtin_amdgcn_s_setprio(1);                                        \
        _Pragma("unroll")                                                     \
        for (int mt = 0; mt < 4; ++mt)                                        \
            _Pragma("unroll")                                                 \
            for (int nt = 0; nt < 4; ++nt)                                    \
                acc[mt][nt] = __builtin_amdgcn_mfma_f32_16x16x32_bf16(        \
                    af[mt], bfb[nt], acc[mt][nt], 0, 0, 0);                   \
        __builtin_amdgcn_s_setprio(0);                                        \
    }

    // prologue: tile 0 staged to buf0; A(1) issued after the sync (stays in flight)
    LOADREGS(0);
    CONVWRITE(0);
    __syncthreads();
    LOADREGS(1);

    int cur = 0;
#pragma unroll 1
    for (int kt = 0; kt < 7; ++kt) {
        COMPUTE2(cur, kt, 0);      // MFMAs cover A(kt+1) arrival
        CONVWRITE(cur ^ 1);        // compiler-counted vmcnt wait for A(kt+1)
        if (kt < 6) LOADREGS(kt + 2);   // 2-deep prefetch into freed regs
        COMPUTE2(cur, kt, 2);      // MFMAs cover ds_write + A(kt+2) issue
        lds_fence_barrier();       // lgkm drain only; A(kt+2) survives barrier
        cur ^= 1;
    }
    COMPUTE2(cur, 7, 0);           // tail tile
    COMPUTE2(cur, 7, 2);

#undef LOADREGS
#undef CONVWRITE
#undef COMPUTE2

    // epilogue: score[row] += sum_a tanh(y + x + b_g + b_s) * v[a]
    float xbv[4], vv[4];
#pragma unroll
    for (int nt = 0; nt < 4; ++nt) {
        int a = wbase + nt * 16 + l15;
        xbv[nt] = xraw[bidx * 512 + a] + b_genes[a] + b_smiles[a];
        vv[nt]  = v[a];
    }
    float rs[4][4];
#pragma unroll
    for (int mt = 0; mt < 4; ++mt)
#pragma unroll
        for (int r = 0; r < 4; ++r)
            rs[mt][r] = 0.f;
#pragma unroll
    for (int mt = 0; mt < 4; ++mt)
#pragma unroll
        for (int nt = 0; nt < 4; ++nt)
#pragma unroll
            for (int r = 0; r < 4; ++r)
                rs[mt][r] += vv[nt] * fast_tanh(acc[mt][nt][r] + xbv[nt]);
#pragma unroll
    for (int mt = 0; mt < 4; ++mt)
#pragma unroll
        for (int r = 0; r < 4; ++r) {
            float s = rs[mt][r];
            s += __shfl_xor(s, 1);
            s += __shfl_xor(s, 2);
            s += __shfl_xor(s, 4);
            s += __shfl_xor(s, 8);
            rs[mt][r] = s;
        }
    if (l15 == 0) {
#pragma unroll
        for (int mt = 0; mt < 4; ++mt)
#pragma unroll
            for (int r = 0; r < 4; ++r)
                atomicAdd(&scores[gm0 + mt * 16 + l4 * 4 + r], rs[mt][r]);
    }
}

// K3: softmax over t per batch
__global__ void k3_softmax(const float* __restrict__ scores, float* __restrict__ alphas) {
    __shared__ float redmax[4], redsum[4];
    int b = blockIdx.x, tid = threadIdx.x;   // 256 threads
    int wave = tid >> 6;
    float sv[8];
    float mx = -1e30f;
#pragma unroll
    for (int i = 0; i < 8; ++i) {
        sv[i] = scores[b * 2048 + i * 256 + tid];
        mx = fmaxf(mx, sv[i]);
    }
#pragma unroll
    for (int m = 32; m >= 1; m >>= 1) mx = fmaxf(mx, __shfl_xor(mx, m));
    if ((tid & 63) == 0) redmax[wave] = mx;
    __syncthreads();
    mx = fmaxf(fmaxf(redmax[0], redmax[1]), fmaxf(redmax[2], redmax[3]));
    float sum = 0.f;
#pragma unroll
    for (int i = 0; i < 8; ++i) {
        sv[i] = __expf(sv[i] - mx);
        sum += sv[i];
    }
#pragma unroll
    for (int m = 32; m >= 1; m >>= 1) sum += __shfl_xor(sum, m);
    if ((tid & 63) == 0) redsum[wave] = sum;
    __syncthreads();
    sum = redsum[0] + redsum[1] + redsum[2] + redsum[3];
    float inv = 1.f / sum;
#pragma unroll
    for (int i = 0; i < 8; ++i) alphas[b * 2048 + i * 256 + tid] = sv[i] * inv;
}

// K4: out[b][h] = sum_t alphas[b][t] * smiles[b][t][h]  (t-split x32, atomic f32)
__global__ void k4_out(const float* __restrict__ smiles,
                       const float* __restrict__ alphas,
                       float* __restrict__ out)
{
    int bx = blockIdx.x;              // 1024 = 32 b * 32 t-chunks
    int b  = bx >> 5;
    int tc = bx & 31;
    int h  = threadIdx.x * 4;         // 256 threads -> 1024 h
    const float* sb = smiles + ((size_t)b * 2048 + tc * 64) * 1024;
    const float* al = alphas + b * 2048 + tc * 64;
    float4 acc = {0.f, 0.f, 0.f, 0.f};
#pragma unroll 4
    for (int t = 0; t < 64; ++t) {
        float a = al[t];
        float4 sv = *(const float4*)(sb + (size_t)t * 1024 + h);
        acc.x += a * sv.x;
        acc.y += a * sv.y;
        acc.z += a * sv.z;
        acc.w += a * sv.w;
    }
    float* o = out + b * 1024 + h;
    atomicAdd(o + 0, acc.x);
    atomicAdd(o + 1, acc.y);
    atomicAdd(o + 2, acc.z);
    atomicAdd(o + 3, acc.w);
}

extern "C" void kernel_launch(void* const* d_in, const int* in_sizes, int n_in,
                              void* d_out, int out_size, void* d_ws, size_t ws_size,
                              hipStream_t stream) {
    const float* genes    = (const float*)d_in[0];
    const float* smiles   = (const float*)d_in[1];
    const float* w_ngf    = (const float*)d_in[2];
    const float* w_genes  = (const float*)d_in[3];
    const float* b_genes  = (const float*)d_in[4];
    const float* w_smiles = (const float*)d_in[5];
    const float* b_smiles = (const float*)d_in[6];
    const float* v        = (const float*)d_in[7];
    float* out = (float*)d_out;

    char* ws = (char*)d_ws;
    unsigned short* Bp = (unsigned short*)(ws);                        // 1 MB packed B
    float* gc     = (float*)(ws + (1 << 20));                          // 256 KB
    float* x      = (float*)(ws + (1 << 20) + (256 << 10));            // 64 KB
    float* scores = (float*)(ws + (1 << 20) + (320 << 10));            // 256 KB
    float* alphas = (float*)(ws + (1 << 20) + (576 << 10));            // 256 KB

    hipMemsetAsync(out, 0, (size_t)32 * 1024 * sizeof(float), stream);
    hipMemsetAsync(x, 0, (size_t)(64 + 256) * 1024, stream);

    k0b_pack<<<1024, 64, 0, stream>>>(w_smiles, Bp);
    k1a_gc<<<256, 256, 0, stream>>>((const float4*)genes, w_ngf, gc);
    k1b_x<<<512, 256, 0, stream>>>(gc, w_genes, x);
    k2_scores<<<1024, 512, 0, stream>>>(smiles, Bp, x, b_genes, b_smiles, v, scores);
    k3_softmax<<<32, 256, 0, stream>>>(scores, alphas);
    k4_out<<<1024, 256, 0, stream>>>(smiles, alphas, out);
}

// Round 5
// 183.045 us; speedup vs baseline: 1.2093x; 1.2093x over previous
//
#include <hip/hip_runtime.h>

// Shapes: genes[32][2048][4], smiles[32][2048][1024], w_ngf[4], w_genes[2048][512],
//         b_genes[512], w_smiles[1024][512], b_smiles[512], v[512] -> out[32][1024]

typedef __bf16 bf16_t;
typedef bf16_t bf16x8 __attribute__((ext_vector_type(8)));
typedef float f32x4 __attribute__((ext_vector_type(4)));

__device__ __forceinline__ unsigned short f32_to_bf16_rne(float f) {
    unsigned int u = __builtin_bit_cast(unsigned int, f);
    u = (u + 0x7FFFu + ((u >> 16) & 1u)) >> 16;
    return (unsigned short)u;
}

__device__ __forceinline__ float fast_tanh(float x) {
    float cx = fminf(fmaxf(x, -30.f), 30.f);
    float e = __expf(2.f * cx);
    return (e - 1.f) / (e + 1.f);
}

// global -> LDS DMA, 16B per lane, wave-uniform LDS base (HW adds lane*16).
#define GLL16(g, l)                                                        \
    __builtin_amdgcn_global_load_lds(                                      \
        (const __attribute__((address_space(1))) void*)(g),                \
        (__attribute__((address_space(3))) void*)(l), 16, 0, 0)

// K0b: pack w_smiles [1024][512] f32 into FRAGMENT-MAJOR bf16 (contiguous 1KB frags).
// Bp[frag=atile*32+gks][lane][e] = w[gks*32 + (lane>>4)*8 + e][atile*16 + (lane&15)]
__global__ void k0b_pack(const float* __restrict__ w, unsigned short* __restrict__ Bp) {
    int bid  = blockIdx.x;        // 1024 = 32 atiles * 32 gks
    int lane = threadIdx.x;       // 64
    int atile = bid >> 5, gks = bid & 31;
    int col = atile * 16 + (lane & 15);
    int k0  = gks * 32 + (lane >> 4) * 8;
    unsigned short us[8];
#pragma unroll
    for (int e = 0; e < 8; ++e)
        us[e] = f32_to_bf16_rne(w[(size_t)(k0 + e) * 512 + col]);
    *(uint4*)(Bp + (size_t)bid * 512 + lane * 8) = *(const uint4*)us;
}

// K1a: gc[b][g] = dot(genes[b][g][0..3], w_ngf)
__global__ void k1a_gc(const float4* __restrict__ genes, const float* __restrict__ wngf,
                       float* __restrict__ gc) {
    int i = blockIdx.x * 256 + threadIdx.x;   // 65536 = 32*2048
    float4 g = genes[i];
    gc[i] = g.x * wngf[0] + g.y * wngf[1] + g.z * wngf[2] + g.w * wngf[3];
}

// K1b: x[b][a] += sum_{g in chunk} gc[b][g] * w_genes[g][a]   (x pre-zeroed)
__global__ void k1b_x(const float* __restrict__ gc, const float* __restrict__ wg,
                      float* __restrict__ x) {
    __shared__ float gcl[256];
    int bx = blockIdx.x;              // 512 = 32 b * 2 a-halves * 8 g-chunks
    int b = bx >> 4, ah = (bx >> 3) & 1, gch = bx & 7;
    int g0 = gch * 256;
    gcl[threadIdx.x] = gc[b * 2048 + g0 + threadIdx.x];
    __syncthreads();
    int a = ah * 256 + threadIdx.x;
    float s = 0.f;
#pragma unroll 8
    for (int g = 0; g < 256; ++g) s += gcl[g] * wg[(size_t)(g0 + g) * 512 + a];
    atomicAdd(&x[b * 512 + a], s);
}

// K2: fused GEMM + tanh + dot(v) -> scores.
// A staged as FP32 via global_load_lds (zero staging registers), double-buffered
// 2x32KB; f32->bf16 conversion happens on the LDS->reg read path.
// Swizzle: LDS dest linear, global source chunk pre-XORed (c ^= row&7); reads
// use the matching XOR on the byte offset (16B granularity).
__global__ __launch_bounds__(512, 4) void k2_scores(
    const float* __restrict__ smiles,
    const unsigned short* __restrict__ Bp,
    const float* __restrict__ xraw,
    const float* __restrict__ b_genes,
    const float* __restrict__ b_smiles,
    const float* __restrict__ v,
    float* __restrict__ scores)
{
    __shared__ char A_lds[2 * 64 * 512];         // 64 KB: 2 bufs x 64 rows x 512B (128 f32)
    const int tid  = threadIdx.x;
    const int wave = tid >> 6;
    const int lane = tid & 63;
    const int l15  = lane & 15;
    const int l4   = lane >> 4;
    const int gm0  = blockIdx.x * 64;            // 1024 blocks
    const int bidx = gm0 >> 11;
    const int wbase = wave * 64;

    // wave's packed-B base: fragments (wave*4+nt)*32 + gks, each 1KB
    const unsigned short* bpp = Bp + (size_t)(wave * 128) * 512 + lane * 8;

    const f32x4 zero4 = {0.f, 0.f, 0.f, 0.f};
    f32x4 acc[4][4];
#pragma unroll
    for (int mt = 0; mt < 4; ++mt)
#pragma unroll
        for (int nt = 0; nt < 4; ++nt)
            acc[mt][nt] = zero4;

    // STAGE: wave w DMAs rows [w*8, w*8+8) of the 64x128-f32 tile (4 issues x 1KB).
    // LDS slot (row, c) receives global chunk (c ^ (row&7)).
#define STAGE(buf, kt)                                                          \
    _Pragma("unroll")                                                           \
    for (int i = 0; i < 4; ++i) {                                               \
        int row = wave * 8 + i * 2 + (lane >> 5);                               \
        int cc  = (lane & 31) ^ (row & 7);                                      \
        const float* g = smiles + (size_t)(gm0 + row) * 1024 + (kt) * 128 + cc * 4; \
        char* l = A_lds + (buf) * 32768 + wave * 4096 + i * 1024;               \
        GLL16(g, l);                                                            \
    }

#define COMPUTE(cur, kt)                                                        \
    _Pragma("unroll")                                                           \
    for (int ks4 = 0; ks4 < 4; ++ks4) {                                         \
        int gks = (kt) * 4 + ks4;                                               \
        bf16x8 af[4], bfb[4];                                                   \
        _Pragma("unroll")                                                       \
        for (int nt = 0; nt < 4; ++nt)                                          \
            bfb[nt] = *(const bf16x8*)(bpp + (nt * 32 + gks) * 512);            \
        _Pragma("unroll")                                                       \
        for (int mt = 0; mt < 4; ++mt) {                                        \
            int row = mt * 16 + l15;                                            \
            int sw  = (row & 7) << 4;                                           \
            int base = (cur) * 32768 + row * 512;                               \
            int off  = ks4 * 128 + l4 * 32;                                     \
            f32x4 x0 = *(const f32x4*)(A_lds + base + (off ^ sw));              \
            f32x4 x1 = *(const f32x4*)(A_lds + base + ((off + 16) ^ sw));       \
            bf16x8 a;                                                           \
            a[0] = (__bf16)x0[0]; a[1] = (__bf16)x0[1];                         \
            a[2] = (__bf16)x0[2]; a[3] = (__bf16)x0[3];                         \
            a[4] = (__bf16)x1[0]; a[5] = (__bf16)x1[1];                         \
            a[6] = (__bf16)x1[2]; a[7] = (__bf16)x1[3];                         \
            af[mt] = a;                                                         \
        }                                                                       \
        __builtin_amdgcn_s_setprio(1);                                          \
        _Pragma("unroll")                                                       \
        for (int mt = 0; mt < 4; ++mt)                                          \
            _Pragma("unroll")                                                   \
            for (int nt = 0; nt < 4; ++nt)                                      \
                acc[mt][nt] = __builtin_amdgcn_mfma_f32_16x16x32_bf16(          \
                    af[mt], bfb[nt], acc[mt][nt], 0, 0, 0);                     \
        __builtin_amdgcn_s_setprio(0);                                          \
    }

    // prologue: DMA tile 0 into buf 0
    STAGE(0, 0);
    __syncthreads();

    int cur = 0;
#pragma unroll 1
    for (int kt = 0; kt < 8; ++kt) {
        if (kt < 7) STAGE(cur ^ 1, kt + 1);   // DMA next tile, in flight across COMPUTE
        COMPUTE(cur, kt);                     // MFMA + on-read cvt hide the DMA latency
        __syncthreads();                      // vmcnt(0)+lgkm(0)+barrier: gll aged ~full tile
        cur ^= 1;
    }

#undef STAGE
#undef COMPUTE

    // epilogue: score[row] += sum_a tanh(y + x + b_g + b_s) * v[a]
    float xbv[4], vv[4];
#pragma unroll
    for (int nt = 0; nt < 4; ++nt) {
        int a = wbase + nt * 16 + l15;
        xbv[nt] = xraw[bidx * 512 + a] + b_genes[a] + b_smiles[a];
        vv[nt]  = v[a];
    }
    float rs[4][4];
#pragma unroll
    for (int mt = 0; mt < 4; ++mt)
#pragma unroll
        for (int r = 0; r < 4; ++r)
            rs[mt][r] = 0.f;
#pragma unroll
    for (int mt = 0; mt < 4; ++mt)
#pragma unroll
        for (int nt = 0; nt < 4; ++nt)
#pragma unroll
            for (int r = 0; r < 4; ++r)
                rs[mt][r] += vv[nt] * fast_tanh(acc[mt][nt][r] + xbv[nt]);
#pragma unroll
    for (int mt = 0; mt < 4; ++mt)
#pragma unroll
        for (int r = 0; r < 4; ++r) {
            float s = rs[mt][r];
            s += __shfl_xor(s, 1);
            s += __shfl_xor(s, 2);
            s += __shfl_xor(s, 4);
            s += __shfl_xor(s, 8);
            rs[mt][r] = s;
        }
    if (l15 == 0) {
#pragma unroll
        for (int mt = 0; mt < 4; ++mt)
#pragma unroll
            for (int r = 0; r < 4; ++r)
                atomicAdd(&scores[gm0 + mt * 16 + l4 * 4 + r], rs[mt][r]);
    }
}

// K3: softmax over t per batch
__global__ void k3_softmax(const float* __restrict__ scores, float* __restrict__ alphas) {
    __shared__ float redmax[4], redsum[4];
    int b = blockIdx.x, tid = threadIdx.x;   // 256 threads
    int wave = tid >> 6;
    float sv[8];
    float mx = -1e30f;
#pragma unroll
    for (int i = 0; i < 8; ++i) {
        sv[i] = scores[b * 2048 + i * 256 + tid];
        mx = fmaxf(mx, sv[i]);
    }
#pragma unroll
    for (int m = 32; m >= 1; m >>= 1) mx = fmaxf(mx, __shfl_xor(mx, m));
    if ((tid & 63) == 0) redmax[wave] = mx;
    __syncthreads();
    mx = fmaxf(fmaxf(redmax[0], redmax[1]), fmaxf(redmax[2], redmax[3]));
    float sum = 0.f;
#pragma unroll
    for (int i = 0; i < 8; ++i) {
        sv[i] = __expf(sv[i] - mx);
        sum += sv[i];
    }
#pragma unroll
    for (int m = 32; m >= 1; m >>= 1) sum += __shfl_xor(sum, m);
    if ((tid & 63) == 0) redsum[wave] = sum;
    __syncthreads();
    sum = redsum[0] + redsum[1] + redsum[2] + redsum[3];
    float inv = 1.f / sum;
#pragma unroll
    for (int i = 0; i < 8; ++i) alphas[b * 2048 + i * 256 + tid] = sv[i] * inv;
}

// K4: out[b][h] = sum_t alphas[b][t] * smiles[b][t][h]  (t-split x32, atomic f32)
__global__ void k4_out(const float* __restrict__ smiles,
                       const float* __restrict__ alphas,
                       float* __restrict__ out)
{
    int bx = blockIdx.x;              // 1024 = 32 b * 32 t-chunks
    int b  = bx >> 5;
    int tc = bx & 31;
    int h  = threadIdx.x * 4;         // 256 threads -> 1024 h
    const float* sb = smiles + ((size_t)b * 2048 + tc * 64) * 1024;
    const float* al = alphas + b * 2048 + tc * 64;
    float4 acc = {0.f, 0.f, 0.f, 0.f};
#pragma unroll 4
    for (int t = 0; t < 64; ++t) {
        float a = al[t];
        float4 sv = *(const float4*)(sb + (size_t)t * 1024 + h);
        acc.x += a * sv.x;
        acc.y += a * sv.y;
        acc.z += a * sv.z;
        acc.w += a * sv.w;
    }
    float* o = out + b * 1024 + h;
    atomicAdd(o + 0, acc.x);
    atomicAdd(o + 1, acc.y);
    atomicAdd(o + 2, acc.z);
    atomicAdd(o + 3, acc.w);
}

extern "C" void kernel_launch(void* const* d_in, const int* in_sizes, int n_in,
                              void* d_out, int out_size, void* d_ws, size_t ws_size,
                              hipStream_t stream) {
    const float* genes    = (const float*)d_in[0];
    const float* smiles   = (const float*)d_in[1];
    const float* w_ngf    = (const float*)d_in[2];
    const float* w_genes  = (const float*)d_in[3];
    const float* b_genes  = (const float*)d_in[4];
    const float* w_smiles = (const float*)d_in[5];
    const float* b_smiles = (const float*)d_in[6];
    const float* v        = (const float*)d_in[7];
    float* out = (float*)d_out;

    char* ws = (char*)d_ws;
    unsigned short* Bp = (unsigned short*)(ws);                        // 1 MB packed B
    float* gc     = (float*)(ws + (1 << 20));                          // 256 KB
    float* x      = (float*)(ws + (1 << 20) + (256 << 10));            // 64 KB
    float* scores = (float*)(ws + (1 << 20) + (320 << 10));            // 256 KB
    float* alphas = (float*)(ws + (1 << 20) + (576 << 10));            // 256 KB

    hipMemsetAsync(out, 0, (size_t)32 * 1024 * sizeof(float), stream);
    hipMemsetAsync(x, 0, (size_t)(64 + 256) * 1024, stream);

    k0b_pack<<<1024, 64, 0, stream>>>(w_smiles, Bp);
    k1a_gc<<<256, 256, 0, stream>>>((const float4*)genes, w_ngf, gc);
    k1b_x<<<512, 256, 0, stream>>>(gc, w_genes, x);
    k2_scores<<<1024, 512, 0, stream>>>(smiles, Bp, x, b_genes, b_smiles, v, scores);
    k3_softmax<<<32, 256, 0, stream>>>(scores, alphas);
    k4_out<<<1024, 256, 0, stream>>>(smiles, alphas, out);
}

// Round 6
// 182.928 us; speedup vs baseline: 1.2100x; 1.0006x over previous
//
#include <hip/hip_runtime.h>

// Shapes: genes[32][2048][4], smiles[32][2048][1024], w_ngf[4], w_genes[2048][512],
//         b_genes[512], w_smiles[1024][512], b_smiles[512], v[512] -> out[32][1024]

typedef __bf16 bf16_t;
typedef bf16_t bf16x8 __attribute__((ext_vector_type(8)));
typedef float f32x16 __attribute__((ext_vector_type(16)));

__device__ __forceinline__ unsigned short f32_to_bf16_rne(float f) {
    unsigned int u = __builtin_bit_cast(unsigned int, f);
    u = (u + 0x7FFFu + ((u >> 16) & 1u)) >> 16;
    return (unsigned short)u;
}

__device__ __forceinline__ float fast_tanh(float x) {
    float cx = fminf(fmaxf(x, -30.f), 30.f);
    float e = __expf(2.f * cx);
    return (e - 1.f) / (e + 1.f);
}

// K0b: pack w_smiles [1024][512] f32 into 32-col FRAGMENT-MAJOR bf16 for
// mfma_32x32x16. Frag f = atile2*64 + gks16 (atile2: 16 x 32-col tiles,
// gks16: 64 k-steps of 16). Bp[f][lane][e] = w[gks16*16+(lane>>5)*8+e][atile2*32+(lane&31)]
__global__ void k0b_pack(const float* __restrict__ w, unsigned short* __restrict__ Bp) {
    int bid  = blockIdx.x;        // 1024 = 16 atile2 * 64 gks16
    int lane = threadIdx.x;       // 64
    int atile2 = bid >> 6, gks16 = bid & 63;
    int col = atile2 * 32 + (lane & 31);
    int k0  = gks16 * 16 + (lane >> 5) * 8;
    unsigned short us[8];
#pragma unroll
    for (int e = 0; e < 8; ++e)
        us[e] = f32_to_bf16_rne(w[(size_t)(k0 + e) * 512 + col]);
    *(uint4*)(Bp + (size_t)bid * 512 + lane * 8) = *(const uint4*)us;
}

// K1a: gc[b][g] = dot(genes[b][g][0..3], w_ngf)
__global__ void k1a_gc(const float4* __restrict__ genes, const float* __restrict__ wngf,
                       float* __restrict__ gc) {
    int i = blockIdx.x * 256 + threadIdx.x;   // 65536 = 32*2048
    float4 g = genes[i];
    gc[i] = g.x * wngf[0] + g.y * wngf[1] + g.z * wngf[2] + g.w * wngf[3];
}

// K1b: x[b][a] += sum_{g in chunk} gc[b][g] * w_genes[g][a]   (x pre-zeroed)
__global__ void k1b_x(const float* __restrict__ gc, const float* __restrict__ wg,
                      float* __restrict__ x) {
    __shared__ float gcl[256];
    int bx = blockIdx.x;              // 512 = 32 b * 2 a-halves * 8 g-chunks
    int b = bx >> 4, ah = (bx >> 3) & 1, gch = bx & 7;
    int g0 = gch * 256;
    gcl[threadIdx.x] = gc[b * 2048 + g0 + threadIdx.x];
    __syncthreads();
    int a = ah * 256 + threadIdx.x;
    float s = 0.f;
#pragma unroll 8
    for (int g = 0; g < 256; ++g) s += gcl[g] * wg[(size_t)(g0 + g) * 512 + a];
    atomicAdd(&x[b * 512 + a], s);
}

// K2: fused GEMM + tanh + dot(v) -> scores, mfma_f32_32x32x16_bf16.
// R3 skeleton: BK=128 double-buffered bf16 LDS (2x16KB), reg-staged A with
// cvt on the store path, one __syncthreads per tile, 1-deep prefetch.
// Wave w covers rows gm0..gm0+63 x cols [w*64, w*64+64) as 2mt x 2nt of 32x32.
// LDS XOR swizzle: byte ^= (row&15)<<4 (bijective over the 16 granules/row).
__global__ __launch_bounds__(512, 4) void k2_scores(
    const float* __restrict__ smiles,
    const unsigned short* __restrict__ Bp,
    const float* __restrict__ xraw,
    const float* __restrict__ b_genes,
    const float* __restrict__ b_smiles,
    const float* __restrict__ v,
    float* __restrict__ scores)
{
    __shared__ char A_lds[2 * 64 * 256];         // 32 KB: 2 bufs x 64 rows x 256B (128 bf16)
    const int tid  = threadIdx.x;
    const int wave = tid >> 6;
    const int lane = tid & 63;
    const int l31  = lane & 31;
    const int hi   = lane >> 5;
    const int gm0  = blockIdx.x * 64;            // 1024 blocks
    const int bidx = gm0 >> 11;
    const int wbase = wave * 64;

    // wave's packed-B: frags (wave*2+nt)*64 + kt*8 + ks16, each 1KB
    const unsigned short* bpp = Bp + (size_t)(wave * 2) * 64 * 512 + lane * 8;

    // staging geometry: thread owns 16 consecutive floats of the 64x128 tile
    const int srow = tid >> 3;                   // 0..63
    const float* sptr = smiles + (size_t)(gm0 + srow) * 1024 + (tid & 7) * 16;
    const int sswz = (srow & 15) << 4;
    char* wr0 = (char*)A_lds + srow * 256 + (((tid & 7) * 32) ^ sswz);
    char* wr1 = (char*)A_lds + srow * 256 + ((((tid & 7) * 32) + 16) ^ sswz);

    float4 st0, st1, st2, st3;

    f32x16 acc[2][2];
#pragma unroll
    for (int mt = 0; mt < 2; ++mt)
#pragma unroll
        for (int nt = 0; nt < 2; ++nt)
#pragma unroll
            for (int r = 0; r < 16; ++r)
                acc[mt][nt][r] = 0.f;

#define LOADREGS(kt)                                   \
    {   const float* p = sptr + (kt) * 128;            \
        st0 = *(const float4*)(p);                     \
        st1 = *(const float4*)(p + 4);                 \
        st2 = *(const float4*)(p + 8);                 \
        st3 = *(const float4*)(p + 12); }

#define CONVWRITE(buf)                                                     \
    {   union { unsigned short us[8]; uint4 u4; } pa, pb;                  \
        pa.us[0] = f32_to_bf16_rne(st0.x); pa.us[1] = f32_to_bf16_rne(st0.y); \
        pa.us[2] = f32_to_bf16_rne(st0.z); pa.us[3] = f32_to_bf16_rne(st0.w); \
        pa.us[4] = f32_to_bf16_rne(st1.x); pa.us[5] = f32_to_bf16_rne(st1.y); \
        pa.us[6] = f32_to_bf16_rne(st1.z); pa.us[7] = f32_to_bf16_rne(st1.w); \
        pb.us[0] = f32_to_bf16_rne(st2.x); pb.us[1] = f32_to_bf16_rne(st2.y); \
        pb.us[2] = f32_to_bf16_rne(st2.z); pb.us[3] = f32_to_bf16_rne(st2.w); \
        pb.us[4] = f32_to_bf16_rne(st3.x); pb.us[5] = f32_to_bf16_rne(st3.y); \
        pb.us[6] = f32_to_bf16_rne(st3.z); pb.us[7] = f32_to_bf16_rne(st3.w); \
        *(uint4*)(wr0 + (buf) * 16384) = pa.u4;                            \
        *(uint4*)(wr1 + (buf) * 16384) = pb.u4; }

#define COMPUTE(cur, kt)                                                        \
    _Pragma("unroll")                                                           \
    for (int ks = 0; ks < 8; ++ks) {                                            \
        bf16x8 af[2], bfb[2];                                                   \
        _Pragma("unroll")                                                       \
        for (int nt = 0; nt < 2; ++nt)                                          \
            bfb[nt] = *(const bf16x8*)(bpp + (size_t)(nt * 64 + (kt) * 8 + ks) * 512); \
        _Pragma("unroll")                                                       \
        for (int mt = 0; mt < 2; ++mt) {                                        \
            int row = mt * 32 + l31;                                            \
            int byteoff = (cur) * 16384 + row * 256 +                           \
                          ((ks * 32 + hi * 16) ^ ((row & 15) << 4));            \
            af[mt] = *(const bf16x8*)(A_lds + byteoff);                         \
        }                                                                       \
        __builtin_amdgcn_s_setprio(1);                                          \
        _Pragma("unroll")                                                       \
        for (int mt = 0; mt < 2; ++mt)                                          \
            _Pragma("unroll")                                                   \
            for (int nt = 0; nt < 2; ++nt)                                      \
                acc[mt][nt] = __builtin_amdgcn_mfma_f32_32x32x16_bf16(          \
                    af[mt], bfb[nt], acc[mt][nt], 0, 0, 0);                     \
        __builtin_amdgcn_s_setprio(0);                                          \
    }

    // prologue: tile 0 staged to buf0
    LOADREGS(0);
    CONVWRITE(0);
    __syncthreads();

    int cur = 0;
#pragma unroll 1
    for (int kt = 0; kt < 7; ++kt) {
        LOADREGS(kt + 1);          // issue early; MFMAs below hide the HBM latency
        COMPUTE(cur, kt);
        CONVWRITE(cur ^ 1);        // compiler-counted vmcnt wait lands here
        __syncthreads();           // one barrier per K-tile
        cur ^= 1;
    }
    COMPUTE(cur, 7);               // tail tile

#undef LOADREGS
#undef CONVWRITE
#undef COMPUTE

    // epilogue: score[row] += sum_a tanh(y + x + b_g + b_s) * v[a]
    // C layout (m74/m101): col = lane&31, row = (r&3) + 8*(r>>2) + 4*hi
    float xbv[2], vv[2];
#pragma unroll
    for (int nt = 0; nt < 2; ++nt) {
        int a = wbase + nt * 32 + l31;
        xbv[nt] = xraw[bidx * 512 + a] + b_genes[a] + b_smiles[a];
        vv[nt]  = v[a];
    }
#pragma unroll
    for (int mt = 0; mt < 2; ++mt) {
        float rs[16];
#pragma unroll
        for (int r = 0; r < 16; ++r) rs[r] = 0.f;
#pragma unroll
        for (int nt = 0; nt < 2; ++nt)
#pragma unroll
            for (int r = 0; r < 16; ++r)
                rs[r] += vv[nt] * fast_tanh(acc[mt][nt][r] + xbv[nt]);
#pragma unroll
        for (int r = 0; r < 16; ++r) {
            float s = rs[r];
            s += __shfl_xor(s, 1);
            s += __shfl_xor(s, 2);
            s += __shfl_xor(s, 4);
            s += __shfl_xor(s, 8);
            s += __shfl_xor(s, 16);
            rs[r] = s;
        }
        if (l31 == 0) {
#pragma unroll
            for (int r = 0; r < 16; ++r) {
                int row = (r & 3) + 8 * (r >> 2) + 4 * hi;
                atomicAdd(&scores[gm0 + mt * 32 + row], rs[r]);
            }
        }
    }
}

// K3: softmax over t per batch
__global__ void k3_softmax(const float* __restrict__ scores, float* __restrict__ alphas) {
    __shared__ float redmax[4], redsum[4];
    int b = blockIdx.x, tid = threadIdx.x;   // 256 threads
    int wave = tid >> 6;
    float sv[8];
    float mx = -1e30f;
#pragma unroll
    for (int i = 0; i < 8; ++i) {
        sv[i] = scores[b * 2048 + i * 256 + tid];
        mx = fmaxf(mx, sv[i]);
    }
#pragma unroll
    for (int m = 32; m >= 1; m >>= 1) mx = fmaxf(mx, __shfl_xor(mx, m));
    if ((tid & 63) == 0) redmax[wave] = mx;
    __syncthreads();
    mx = fmaxf(fmaxf(redmax[0], redmax[1]), fmaxf(redmax[2], redmax[3]));
    float sum = 0.f;
#pragma unroll
    for (int i = 0; i < 8; ++i) {
        sv[i] = __expf(sv[i] - mx);
        sum += sv[i];
    }
#pragma unroll
    for (int m = 32; m >= 1; m >>= 1) sum += __shfl_xor(sum, m);
    if ((tid & 63) == 0) redsum[wave] = sum;
    __syncthreads();
    sum = redsum[0] + redsum[1] + redsum[2] + redsum[3];
    float inv = 1.f / sum;
#pragma unroll
    for (int i = 0; i < 8; ++i) alphas[b * 2048 + i * 256 + tid] = sv[i] * inv;
}

// K4: out[b][h] = sum_t alphas[b][t] * smiles[b][t][h]  (t-split x32, atomic f32)
__global__ void k4_out(const float* __restrict__ smiles,
                       const float* __restrict__ alphas,
                       float* __restrict__ out)
{
    int bx = blockIdx.x;              // 1024 = 32 b * 32 t-chunks
    int b  = bx >> 5;
    int tc = bx & 31;
    int h  = threadIdx.x * 4;         // 256 threads -> 1024 h
    const float* sb = smiles + ((size_t)b * 2048 + tc * 64) * 1024;
    const float* al = alphas + b * 2048 + tc * 64;
    float4 acc = {0.f, 0.f, 0.f, 0.f};
#pragma unroll 4
    for (int t = 0; t < 64; ++t) {
        float a = al[t];
        float4 sv = *(const float4*)(sb + (size_t)t * 1024 + h);
        acc.x += a * sv.x;
        acc.y += a * sv.y;
        acc.z += a * sv.z;
        acc.w += a * sv.w;
    }
    float* o = out + b * 1024 + h;
    atomicAdd(o + 0, acc.x);
    atomicAdd(o + 1, acc.y);
    atomicAdd(o + 2, acc.z);
    atomicAdd(o + 3, acc.w);
}

extern "C" void kernel_launch(void* const* d_in, const int* in_sizes, int n_in,
                              void* d_out, int out_size, void* d_ws, size_t ws_size,
                              hipStream_t stream) {
    const float* genes    = (const float*)d_in[0];
    const float* smiles   = (const float*)d_in[1];
    const float* w_ngf    = (const float*)d_in[2];
    const float* w_genes  = (const float*)d_in[3];
    const float* b_genes  = (const float*)d_in[4];
    const float* w_smiles = (const float*)d_in[5];
    const float* b_smiles = (const float*)d_in[6];
    const float* v        = (const float*)d_in[7];
    float* out = (float*)d_out;

    char* ws = (char*)d_ws;
    unsigned short* Bp = (unsigned short*)(ws);                        // 1 MB packed B
    float* gc     = (float*)(ws + (1 << 20));                          // 256 KB
    float* x      = (float*)(ws + (1 << 20) + (256 << 10));            // 64 KB
    float* scores = (float*)(ws + (1 << 20) + (320 << 10));            // 256 KB
    float* alphas = (float*)(ws + (1 << 20) + (576 << 10));            // 256 KB

    hipMemsetAsync(out, 0, (size_t)32 * 1024 * sizeof(float), stream);
    hipMemsetAsync(x, 0, (size_t)(64 + 256) * 1024, stream);

    k0b_pack<<<1024, 64, 0, stream>>>(w_smiles, Bp);
    k1a_gc<<<256, 256, 0, stream>>>((const float4*)genes, w_ngf, gc);
    k1b_x<<<512, 256, 0, stream>>>(gc, w_genes, x);
    k2_scores<<<1024, 512, 0, stream>>>(smiles, Bp, x, b_genes, b_smiles, v, scores);
    k3_softmax<<<32, 256, 0, stream>>>(scores, alphas);
    k4_out<<<1024, 256, 0, stream>>>(smiles, alphas, out);
}